// Round 22
// baseline (292.443 us; speedup 1.0000x reference)
//
#include <hip/hip_runtime.h>
#include <hip/hip_bf16.h>
#include <math.h>

#define NB 4096
#define DC 256
#define PC 512

typedef unsigned short ushort_t;
typedef __attribute__((ext_vector_type(4))) unsigned short us4;
typedef __attribute__((ext_vector_type(8))) unsigned short us8;
typedef __attribute__((ext_vector_type(8))) short s8v;       // bf16x8 for MFMA
typedef __attribute__((ext_vector_type(4))) float f32x4;

__device__ __forceinline__ float bf16_to_f(ushort_t u) {
    union { unsigned int i; float f; } c;
    c.i = ((unsigned int)u) << 16;
    return c.f;
}
__device__ __forceinline__ ushort_t f2bf(float f) {          // RNE
    union { float f; unsigned int u; } c; c.f = f;
    unsigned int r = c.u + 0x7fffu + ((c.u >> 16) & 1u);
    return (ushort_t)(r >> 16);
}

// ---------------- K_pre: all small packing kernels merged (blockIdx-range dispatch) -------
__global__ __launch_bounds__(256) void k_pre(
    const float* __restrict__ proto, float* __restrict__ p2,
    ushort_t* __restrict__ pfragHi, ushort_t* __restrict__ pfragLo,
    const float* __restrict__ w3, ushort_t* __restrict__ w3fH, ushort_t* __restrict__ w3fL,
    const float* __restrict__ w2, ushort_t* __restrict__ w2fH, ushort_t* __restrict__ w2fL,
    const float* __restrict__ wd1, ushort_t* __restrict__ wd1frag,
    const float* __restrict__ wup, ushort_t* __restrict__ wupfH, ushort_t* __restrict__ wupfL)
{
    int b = blockIdx.x, tid = threadIdx.x;
    __shared__ float red[256];
    if (b < 512) {
        int p = b, d = tid;
        float v = proto[p * DC + d];
        red[d] = v * v;
        __syncthreads();
        for (int s = 128; s > 0; s >>= 1) {
            if (d < s) red[d] += red[d + s];
            __syncthreads();
        }
        if (d == 0) p2[p] = red[0];
    } else if (b < 1024) {
        int idx = (b - 512) * 256 + tid;
        int j = idx & 7, l = (idx >> 3) & 63;
        int k0 = (idx >> 9) & 7, nt = idx >> 12;
        int n = nt * 16 + (l & 15);
        int k = k0 * 32 + (l >> 4) * 8 + j;
        float v = proto[n * DC + k];
        ushort_t hi = f2bf(v);
        pfragHi[idx] = hi;
        pfragLo[idx] = f2bf(v - bf16_to_f(hi));
    } else if (b < 1184) {
        int idx = (b - 1024) * 256 + tid;
        int j = idx & 7, l = (idx >> 3) & 63;
        int q = idx >> 9;
        int k0 = q % 5, nt = q / 5;
        int d = nt * 16 + (l & 15);
        int k = k0 * 32 + (l >> 4) * 8 + j;
        float v = (k < 144) ? w3[d * 144 + k] : 0.f;
        ushort_t hi = f2bf(v);
        w3fH[idx] = hi;
        w3fL[idx] = f2bf(v - bf16_to_f(hi));
    } else if (b < 1190) {
        int idx = (b - 1184) * 256 + tid;
        int j = idx & 7, l = (idx >> 3) & 63;
        int k0 = idx >> 9;
        int ch = l & 15;
        int k = k0 * 32 + (l >> 4) * 8 + j;
        float v = (k < 72) ? w2[ch * 72 + k] : 0.f;
        ushort_t hi = f2bf(v);
        w2fH[idx] = hi;
        w2fL[idx] = f2bf(v - bf16_to_f(hi));
    } else if (b < 1334) {
        int idx = (b - 1190) * 256 + tid;
        int j = idx & 7, l = (idx >> 3) & 63;
        int k0 = (idx >> 9) & 7, nt = idx >> 12;
        int n = nt * 16 + (l & 15);
        int k = k0 * 32 + (l >> 4) * 8 + j;
        wd1frag[idx] = f2bf(wd1[k * 144 + n]);
    } else {
        int idx = (b - 1334) * 256 + tid;
        int j = idx & 7, l = (idx >> 3) & 63;
        int k0 = (idx >> 9) & 7, nt = idx >> 12;
        int np = nt * 16 + (l & 15);
        int d = k0 * 32 + (l >> 4) * 8 + j;
        int pos = np >> 8, ch = np & 255;
        float v = wup[d * 6400 + ch * 25 + pos];
        ushort_t hi = f2bf(v);
        wupfH[idx] = hi;
        wupfL[idx] = f2bf(v - bf16_to_f(hi));
    }
}

// ---------------- K0f: PW = proto x wupT via MFMA (hi/lo), -> PWfrag [400][16][64][8] -----
__global__ __launch_bounds__(256) void k_pw2(
    const ushort_t* __restrict__ pfragHi, const ushort_t* __restrict__ pfragLo,
    const ushort_t* __restrict__ wupfH, const ushort_t* __restrict__ wupfL,
    ushort_t* __restrict__ PWfrag)
{
    int t = threadIdx.x;
    int w = t >> 6, l = t & 63, lr = l & 15, lg = l >> 4;
    int my = blockIdx.y;
    int ntb = blockIdx.x * 16 + w * 4;
    const s8v* AH = (const s8v*)pfragHi;
    const s8v* AL = (const s8v*)pfragLo;
    const s8v* BH = (const s8v*)wupfH;
    const s8v* BL = (const s8v*)wupfL;
    f32x4 acc[4];
#pragma unroll
    for (int q = 0; q < 4; q++) acc[q] = (f32x4){0.f, 0.f, 0.f, 0.f};
#pragma unroll
    for (int k0 = 0; k0 < 8; k0++) {
        s8v ah = AH[(my * 8 + k0) * 64 + l];
        s8v al = AL[(my * 8 + k0) * 64 + l];
#pragma unroll
        for (int q = 0; q < 4; q++) {
            s8v bh = BH[(size_t)((ntb + q) * 8 + k0) * 64 + l];
            s8v bl = BL[(size_t)((ntb + q) * 8 + k0) * 64 + l];
            acc[q] = __builtin_amdgcn_mfma_f32_16x16x32_bf16(ah, bh, acc[q], 0, 0, 0);
            acc[q] = __builtin_amdgcn_mfma_f32_16x16x32_bf16(al, bh, acc[q], 0, 0, 0);
            acc[q] = __builtin_amdgcn_mfma_f32_16x16x32_bf16(ah, bl, acc[q], 0, 0, 0);
        }
    }
#pragma unroll
    for (int q = 0; q < 4; q++) {
        int nt = ntb + q;
#pragma unroll
        for (int r = 0; r < 4; r++) {
            int p = my * 16 + lg * 4 + r;
            int k0p = p >> 5;
            int ll = ((p >> 3) & 3) * 16 + lr;
            int jj = p & 7;
            PWfrag[(((size_t)(nt * 16 + k0p) * 64) + ll) * 8 + jj] = f2bf(acc[q][r]);
        }
    }
}

// ---------------- E1: 2 img/block, 1024 thr; conv phases at 512 thr/img; coalesced store --
__global__ __launch_bounds__(1024) void k_enc1(
    const float* __restrict__ x,
    const float* __restrict__ w1, const float* __restrict__ b1,
    const ushort_t* __restrict__ w2fH, const ushort_t* __restrict__ w2fL,
    const float* __restrict__ b2,
    const float* __restrict__ g2, const float* __restrict__ bt2,
    const ushort_t* __restrict__ w3fH, const ushort_t* __restrict__ w3fL,
    const float* __restrict__ b3,
    ushort_t* __restrict__ h3g)        // [4096][25][256] bf16
{
    int b0 = blockIdx.x * 2;
    int t = threadIdx.x;
    int w = t >> 6, l = t & 63, lr = l & 15, lg = l >> 4;
    int tim = t >> 9, tt = t & 511;       // thread-half image

    __shared__ __align__(16) unsigned char buf[51712];
    unsigned char* bufI = buf + tim * 25856;
    float* xb = (float*)bufI;
    float* h1 = (float*)(bufI + 3136);
    ushort_t* im2Hi = (ushort_t*)(bufI + 9408);
    float* h2 = (float*)(bufI + 22720);
    ushort_t* imHi = (ushort_t*)bufI;

    const float bnr = rsqrtf(1.0f + 1e-5f);

    // phase 0: load x, zero im2col2 region
    const float* xg = x + (size_t)(b0 + tim) * 784;
    for (int i = tt; i < 784; i += 512) xb[i] = xg[i];
    for (int i = tt; i < 832; i += 512)
        ((float4*)(bufI + 9408))[i] = (float4){0.f, 0.f, 0.f, 0.f};
    __syncthreads();

    // phase 1: conv1 + scatter into im2col2 (single bf16), 512 thr/img
    for (int o = tt; o < 1568; o += 512) {
        int c = o / 196, r = o % 196, y = r / 14, xc = r % 14;
        float acc = b1[c];
        for (int sy = 0; sy < 3; sy++) {
            int iy = 2 * y - 1 + sy;
            if ((unsigned)iy >= 28u) continue;
            for (int sx = 0; sx < 3; sx++) {
                int ix = 2 * xc - 1 + sx;
                if ((unsigned)ix >= 28u) continue;
                acc += w1[c * 9 + sy * 3 + sx] * xb[iy * 28 + ix];
            }
        }
        float v = fmaxf(acc, 0.f);
        ushort_t hi = f2bf(v);
        int kb = c * 9;
        int yA, syA, xA, sxA, yB = 0, xB = 0;
        bool hasYB, hasXB;
        if (y & 1) { yA = y >> 1; syA = 2; yB = yA + 1; hasYB = (yB < 7); }
        else       { yA = y >> 1; syA = 1; hasYB = false; }
        if (xc & 1) { xA = xc >> 1; sxA = 2; xB = xA + 1; hasXB = (xB < 7); }
        else        { xA = xc >> 1; sxA = 1; hasXB = false; }
        im2Hi[(yA * 7 + xA) * 104 + kb + syA * 3 + sxA] = hi;
        if (hasXB) im2Hi[(yA * 7 + xB) * 104 + kb + syA * 3] = hi;
        if (hasYB) {
            im2Hi[(yB * 7 + xA) * 104 + kb + sxA] = hi;
            if (hasXB) im2Hi[(yB * 7 + xB) * 104 + kb] = hi;
        }
    }
    __syncthreads();

    // phase 2: conv2 as MFMA — waves (w&7)<4 of each half (4 m-tiles per image)
    if ((w & 7) < 4) {
        int w4 = w & 3;
        f32x4 cc = {0, 0, 0, 0};
        const s8v* WH = (const s8v*)w2fH;
        const s8v* WL = (const s8v*)w2fL;
#pragma unroll
        for (int k0 = 0; k0 < 3; k0++) {
            s8v a0 = *(const s8v*)&im2Hi[(w4 * 16 + lr) * 104 + k0 * 32 + lg * 8];
            s8v bh = WH[k0 * 64 + l];
            s8v bl = WL[k0 * 64 + l];
            cc = __builtin_amdgcn_mfma_f32_16x16x32_bf16(a0, bh, cc, 0, 0, 0);
            cc = __builtin_amdgcn_mfma_f32_16x16x32_bf16(a0, bl, cc, 0, 0, 0);
        }
        int ch = lr;
        float s = g2[ch] * bnr, bb = b2[ch], bt = bt2[ch];
#pragma unroll
        for (int r = 0; r < 4; r++) {
            int pos = w4 * 16 + lg * 4 + r;
            if (pos < 49)
                h2[ch * 49 + pos] = fmaxf((cc[r] + bb) * s + bt, 0.f);
        }
    }
    __syncthreads();

    // phase 3: scatter h2 -> im2col3 (single bf16) + extended k-tail zero guard
    if (tt < 64) imHi[3600 + tt] = 0;
    for (int o = tt; o < 784; o += 512) {
        float v = h2[o];
        int ci = o / 49, rr = o % 49, iy = rr / 7, ixp = rr % 7;
        ushort_t hi = f2bf(v);
        int kb = ci * 9;
#pragma unroll
        for (int sy = 0; sy < 3; sy++) {
            int py = iy - sy;
            if ((unsigned)py < 5u) {
#pragma unroll
                for (int sx = 0; sx < 3; sx++) {
                    int px = ixp - sx;
                    if ((unsigned)px < 5u)
                        imHi[(py * 5 + px) * 144 + kb + sy * 3 + sx] = hi;
                }
            }
        }
    }
    __syncthreads();

    // phase 4: conv3 as MFMA — wave w owns nt=w for BOTH images (16 waves = 16 nt)
    {
        const ushort_t* imHi0 = (const ushort_t*)buf;
        const ushort_t* imHi1 = (const ushort_t*)(buf + 25856);
        int nt = w;
        f32x4 c[2][2];   // [im][mt]
#pragma unroll
        for (int im = 0; im < 2; im++)
#pragma unroll
            for (int mt = 0; mt < 2; mt++) c[im][mt] = (f32x4){0.f, 0.f, 0.f, 0.f};
        const s8v* WH = (const s8v*)w3fH;
        const s8v* WL = (const s8v*)w3fL;
#pragma unroll
        for (int k0 = 0; k0 < 5; k0++) {
            s8v a00 = *(const s8v*)&imHi0[lr * 144 + k0 * 32 + lg * 8];
            s8v a01 = *(const s8v*)&imHi0[(16 + lr) * 144 + k0 * 32 + lg * 8];
            s8v a10 = *(const s8v*)&imHi1[lr * 144 + k0 * 32 + lg * 8];
            s8v a11 = *(const s8v*)&imHi1[(16 + lr) * 144 + k0 * 32 + lg * 8];
            s8v bh = WH[(nt * 5 + k0) * 64 + l];
            s8v bl = WL[(nt * 5 + k0) * 64 + l];
            c[0][0] = __builtin_amdgcn_mfma_f32_16x16x32_bf16(a00, bh, c[0][0], 0, 0, 0);
            c[0][1] = __builtin_amdgcn_mfma_f32_16x16x32_bf16(a01, bh, c[0][1], 0, 0, 0);
            c[0][0] = __builtin_amdgcn_mfma_f32_16x16x32_bf16(a00, bl, c[0][0], 0, 0, 0);
            c[0][1] = __builtin_amdgcn_mfma_f32_16x16x32_bf16(a01, bl, c[0][1], 0, 0, 0);
            c[1][0] = __builtin_amdgcn_mfma_f32_16x16x32_bf16(a10, bh, c[1][0], 0, 0, 0);
            c[1][1] = __builtin_amdgcn_mfma_f32_16x16x32_bf16(a11, bh, c[1][1], 0, 0, 0);
            c[1][0] = __builtin_amdgcn_mfma_f32_16x16x32_bf16(a10, bl, c[1][0], 0, 0, 0);
            c[1][1] = __builtin_amdgcn_mfma_f32_16x16x32_bf16(a11, bl, c[1][1], 0, 0, 0);
        }
        __syncthreads();   // all A-reads done; h3s overlays imHi regions
        int d = nt * 16 + lr;
        float bb = b3[d];
#pragma unroll
        for (int im = 0; im < 2; im++) {
            ushort_t* hs = (ushort_t*)(buf + im * 25856);
#pragma unroll
            for (int mt = 0; mt < 2; mt++) {
                f32x4 cv = c[im][mt];
#pragma unroll
                for (int r = 0; r < 4; r++) {
                    int pos = mt * 16 + lg * 4 + r;
                    if (pos < 25) {
                        float h = fmaxf(cv[r] + bb, 0.f);
                        hs[pos * 256 + d] = f2bf(h);
                    }
                }
            }
        }
    }
    __syncthreads();

    // phase 5: coalesced us8 copy LDS h3s -> global h3g
    for (int i = t; i < 1600; i += 1024) {
        int im = i >= 800 ? 1 : 0;
        int idx = im ? i - 800 : i;
        *(us8*)&h3g[(size_t)(b0 + im) * 6400 + idx * 8] =
            *(const us8*)((const ushort_t*)(buf + im * 25856) + idx * 8);
    }
}

// ---------------- E2: MFMA distances + softmax (2 img/block; proto HI-ONLY) --------------
__global__ __launch_bounds__(1024) void k_enc2(
    const ushort_t* __restrict__ h3g,        // [4096][25][256] bf16
    const ushort_t* __restrict__ pfragHi,
    const float* __restrict__ p2,
    float* __restrict__ md_out,
    ushort_t* __restrict__ Wsm)
{
    int t = threadIdx.x;
    int b0 = blockIdx.x * 2;
    int w = t >> 6, l = t & 63, lr = l & 15, lg = l >> 4;

    __shared__ __align__(16) ushort_t h3s[2][32][264];   // 33792 B
    __shared__ float mds[2][512];
    __shared__ float x2sh[2][32];
    __shared__ float x2part[2][25][8];
    __shared__ float wred[2][16];

    for (int i = t; i < 2048; i += 1024) {
        int im = i >> 10, pos = (i >> 5) & 31, c8 = i & 31;
        us8 v = {0, 0, 0, 0, 0, 0, 0, 0};
        if (pos < 25)
            v = *(const us8*)&h3g[(size_t)(b0 + im) * 6400 + pos * 256 + c8 * 8];
        *(us8*)&h3s[im][pos][c8 * 8] = v;
    }
    __syncthreads();

    if (t < 400) {
        int im = t / 200, rest = t % 200;
        int pos = rest >> 3, ch = rest & 7;
        const ushort_t* hp = &h3s[im][pos][ch * 32];
        float s = 0.f;
#pragma unroll
        for (int i = 0; i < 32; i++) {
            float f = bf16_to_f(hp[i]);
            s = fmaf(f, f, s);
        }
        x2part[im][pos][ch] = s;
    }
    __syncthreads();
    if (t < 64) {
        int im = t >> 5, pos = t & 31;
        float s = 1e30f;
        if (pos < 25) {
            s = 0.f;
#pragma unroll
            for (int c = 0; c < 8; c++) s += x2part[im][pos][c];
        }
        x2sh[im][pos] = s;
    }
    __syncthreads();

    {
        f32x4 acc[2][2][2];
#pragma unroll
        for (int i = 0; i < 2; i++)
#pragma unroll
            for (int jm = 0; jm < 2; jm++)
#pragma unroll
                for (int mt = 0; mt < 2; mt++) acc[i][jm][mt] = (f32x4){0.f, 0.f, 0.f, 0.f};
        const s8v* BH = (const s8v*)pfragHi;
        s8v bhc[2], bhn[2];
#pragma unroll
        for (int ntq = 0; ntq < 2; ntq++) {
            int nt = w * 2 + ntq;
            bhc[ntq] = BH[(nt * 8 + 0) * 64 + l];
        }
        for (int k0 = 0; k0 < 8; k0++) {
            if (k0 < 7) {
#pragma unroll
                for (int ntq = 0; ntq < 2; ntq++) {
                    int nt = w * 2 + ntq;
                    bhn[ntq] = BH[(nt * 8 + k0 + 1) * 64 + l];
                }
            }
            s8v ah[2][2];
            ah[0][0] = *(const s8v*)&h3s[0][lr][k0 * 32 + lg * 8];
            ah[0][1] = *(const s8v*)&h3s[0][16 + lr][k0 * 32 + lg * 8];
            ah[1][0] = *(const s8v*)&h3s[1][lr][k0 * 32 + lg * 8];
            ah[1][1] = *(const s8v*)&h3s[1][16 + lr][k0 * 32 + lg * 8];
#pragma unroll
            for (int ntq = 0; ntq < 2; ntq++) {
                s8v bh = bhc[ntq];
#pragma unroll
                for (int im = 0; im < 2; im++) {
                    acc[ntq][im][0] = __builtin_amdgcn_mfma_f32_16x16x32_bf16(ah[im][0], bh, acc[ntq][im][0], 0, 0, 0);
                    acc[ntq][im][1] = __builtin_amdgcn_mfma_f32_16x16x32_bf16(ah[im][1], bh, acc[ntq][im][1], 0, 0, 0);
                }
            }
#pragma unroll
            for (int ntq = 0; ntq < 2; ntq++) bhc[ntq] = bhn[ntq];
        }
        float x2r[2][8];
#pragma unroll
        for (int im = 0; im < 2; im++)
#pragma unroll
            for (int r = 0; r < 4; r++) {
                x2r[im][r]     = x2sh[im][lg * 4 + r];
                x2r[im][4 + r] = x2sh[im][16 + lg * 4 + r];
            }
#pragma unroll
        for (int ntq = 0; ntq < 2; ntq++) {
            int pcol = (w * 2 + ntq) * 16 + lr;
            float p2v = p2[pcol];
#pragma unroll
            for (int im = 0; im < 2; im++) {
                float mm = 1e30f;
#pragma unroll
                for (int r = 0; r < 4; r++) {
                    float d0 = fmaxf(x2r[im][r]     - 2.f * acc[ntq][im][0][r] + p2v, 0.f);
                    float d1 = fmaxf(x2r[im][4 + r] - 2.f * acc[ntq][im][1][r] + p2v, 0.f);
                    mm = fminf(mm, fminf(d0, d1));
                }
                mm = fminf(mm, __shfl_xor(mm, 16));
                mm = fminf(mm, __shfl_xor(mm, 32));
                if (lg == 0) mds[im][pcol] = mm;
            }
        }
    }
    __syncthreads();

    int img = t >> 9, tt = t & 511;
    float mind = mds[img][tt];
    md_out[(size_t)(b0 + img) * PC + tt] = mind;
    float a = -mind;
    float mx = a;
#pragma unroll
    for (int off = 1; off < 64; off <<= 1) mx = fmaxf(mx, __shfl_xor(mx, off));
    int wv = w & 7;
    if (l == 0) wred[img][wv] = mx;
    __syncthreads();
    float m = wred[img][0];
#pragma unroll
    for (int i = 1; i < 8; i++) m = fmaxf(m, wred[img][i]);
    float e = expf(a - m);
    float sm = e;
#pragma unroll
    for (int off = 1; off < 64; off <<= 1) sm += __shfl_xor(sm, off);
    if (l == 0) wred[img][8 + wv] = sm;
    __syncthreads();
    float ssum = wred[img][8];
#pragma unroll
    for (int i = 9; i < 16; i++) ssum += wred[img][i];
    Wsm[(size_t)(b0 + img) * PC + tt] = f2bf(e / ssum);
}

// ---------------- K2: zupT = Wsm x PW (bf16 MFMA, 2-slab staging), bias+bn+relu ----------
__global__ __launch_bounds__(512) void k_zup2(
    const ushort_t* __restrict__ Wsm,      // [4096][512]
    const ushort_t* __restrict__ PWfrag,   // [400][16][64][8]
    const float* __restrict__ bup, const float* __restrict__ gup,
    const float* __restrict__ btup,
    ushort_t* __restrict__ zupT)           // [4096][6400]
{
    __shared__ __align__(16) ushort_t Bsh[2][8192];
    int t = threadIdx.x;
    int w = t >> 6, l = t & 63;
    int n0 = blockIdx.x * 128;             // 50
    int m0 = blockIdx.y * 128;             // 32
    int row = m0 + w * 16 + (l & 15);
    int krow = (l >> 4) * 8;
    f32x4 acc[8];
#pragma unroll
    for (int i = 0; i < 8; i++) acc[i] = (f32x4){0.f, 0.f, 0.f, 0.f};
    const s8v* B = (const s8v*)PWfrag;
    int base = blockIdx.x * 8 * 16;

    {
        s8v v0 = B[(size_t)(base + (t >> 6) * 16 + 0) * 64 + (t & 63)];
        s8v v1 = B[(size_t)(base + (t >> 6) * 16 + 1) * 64 + (t & 63)];
        *(s8v*)&Bsh[0][t * 8] = v0;
        *(s8v*)&Bsh[0][4096 + t * 8] = v1;
    }
    __syncthreads();
    for (int r = 0; r < 8; r++) {
        int cur = r & 1;
        if (r < 7) {
            s8v v0 = B[(size_t)(base + (t >> 6) * 16 + 2 * r + 2) * 64 + (t & 63)];
            s8v v1 = B[(size_t)(base + (t >> 6) * 16 + 2 * r + 3) * 64 + (t & 63)];
            *(s8v*)&Bsh[cur ^ 1][t * 8] = v0;
            *(s8v*)&Bsh[cur ^ 1][4096 + t * 8] = v1;
        }
#pragma unroll
        for (int kk = 0; kk < 2; kk++) {
            int k0 = 2 * r + kk;
            s8v a = *(const s8v*)&Wsm[(size_t)row * 512 + k0 * 32 + krow];
#pragma unroll
            for (int nt = 0; nt < 8; nt++) {
                s8v bb = *(const s8v*)&Bsh[cur][kk * 4096 + (nt * 64 + l) * 8];
                acc[nt] = __builtin_amdgcn_mfma_f32_16x16x32_bf16(a, bb, acc[nt], 0, 0, 0);
            }
        }
        __syncthreads();
    }

    const float bnr = rsqrtf(1.0f + 1e-5f);
    int rowbase = m0 + w * 16 + (l >> 4) * 4;
#pragma unroll
    for (int nt = 0; nt < 8; nt++) {
        int n = n0 + nt * 16 + (l & 15);
        int ch = n & 255;
        float sc = gup[ch] * bnr, bb = bup[ch], bt = btup[ch];
#pragma unroll
        for (int r = 0; r < 4; r++) {
            float v = (acc[nt][r] + bb) * sc + bt;
            zupT[(size_t)(rowbase + r) * 6400 + n] = f2bf(fmaxf(v, 0.f));
        }
    }
}

// ---------------- wd2/wd3 load-balanced class pieces ----------------
template<int CLS, int NCO>
__device__ __forceinline__ void wd2_piece(
    const float* hb, float* hout, const float* w2sT,
    const float* bd2, const float* gd2, const float* btd2,
    float bnr, int r, int c, int co0)
{
    const int cy = CLS >> 1, cx = CLS & 1;
    float acc[NCO];
#pragma unroll
    for (int q = 0; q < NCO; q++) acc[q] = 0.f;
#pragma unroll
    for (int ty = 0; ty < 1 + cy; ty++) {
        int iy = r + ty;
        int sy = cy ? (ty ? 0 : 2) : 1;
#pragma unroll
        for (int tx = 0; tx < 1 + cx; tx++) {
            int ix = c + tx;
            int sx = cx ? (tx ? 0 : 2) : 1;
            const float* wp = &w2sT[(sy * 3 + sx) * 128];
            int hoff = iy * 8 + ix;
            float h[16];
#pragma unroll
            for (int ci = 0; ci < 16; ci++) h[ci] = hb[ci * 64 + hoff];
#pragma unroll
            for (int q = 0; q < NCO; q++) {
                const float* wc = &wp[(co0 + q) * 16];
                float a = acc[q];
#pragma unroll
                for (int ci = 0; ci < 16; ci++) a = fmaf(h[ci], wc[ci], a);
                acc[q] = a;
            }
        }
    }
    int y = 2 * r + cy, x = 2 * c + cx;
#pragma unroll
    for (int q = 0; q < NCO; q++) {
        int co = co0 + q;
        float v = (acc[q] + bd2[co]) * (gd2[co] * bnr) + btd2[co];
        hout[co * 225 + y * 15 + x] = fmaxf(v, 0.f);
    }
}

template<int CLS, int NROW>
__device__ __forceinline__ void wd3_piece(
    const float* h2b, const float* w3sT, float bd30,
    float* og, int l, int row0)
{
    const int cy = CLS >> 1, cx = CLS & 1;
    const int NIT = (NROW * 16 + 63) / 64;
#pragma unroll
    for (int j = 0; j < NIT; j++) {
        int idx = l + 64 * j;
        int row = idx >> 4, col = idx & 15;
        if (row < NROW && col < 14) {
            int rr = row0 + row;
            float a = bd30;
#pragma unroll
            for (int ty = 0; ty < 1 + cy; ty++) {
                int iy = rr + ty;
                int sy = cy ? (ty ? 0 : 2) : 1;
#pragma unroll
                for (int tx = 0; tx < 1 + cx; tx++) {
                    int ix = col + tx;
                    int sx = cx ? (tx ? 0 : 2) : 1;
                    const float* wp = &w3sT[(sy * 3 + sx) * 8];
                    int hoff = iy * 15 + ix;
#pragma unroll
                    for (int ci = 0; ci < 8; ci++)
                        a = fmaf(h2b[ci * 225 + hoff], wp[ci], a);
                }
            }
            int y = 2 * rr + cy, x = 2 * col + cx;
            og[y * 28 + x] = 1.f / (1.f + expf(-a));
        }
    }
}

// ---------------- K3: fused decoder, 2 img/block, scatter-epilogue (no Ps/gather) ---------
__global__ __launch_bounds__(512) void k_dtail(
    const ushort_t* __restrict__ zupT,     // [4096][6400]
    const ushort_t* __restrict__ wd1frag,  // [9][8][64][8]
    const float* __restrict__ bd1, const float* __restrict__ gd1, const float* __restrict__ btd1,
    const float* __restrict__ wd2, const float* __restrict__ bd2,
    const float* __restrict__ gd2, const float* __restrict__ btd2,
    const float* __restrict__ wd3, const float* __restrict__ bd3,
    float* __restrict__ out0)
{
    int b0 = blockIdx.x * 2, t = threadIdx.x;
    int w = t >> 6, l = t & 63, lr = l & 15, lg = l >> 4;
    int g = w >> 2, wv = w & 3, tg = t & 255;
    __shared__ __align__(16) unsigned char dbuf[33792];   // zA[2] -> later hd2p[2]
    __shared__ float hd1p[2][16][64];
    __shared__ float w2sT[9 * 8 * 16];
    __shared__ float w3sT[9 * 8];
    ushort_t* zAb = (ushort_t*)dbuf;

    const float bnr = rsqrtf(1.0f + 1e-5f);

    for (int c = t; c < 1600; c += 512) {
        int im = c / 800, cc = c % 800;
        *(us8*)&zAb[im * 8448 + (cc >> 5) * 264 + (cc & 31) * 8] =
            *(const us8*)&zupT[(size_t)(b0 + im) * 6400 + cc * 8];
    }
    for (int i = t; i < 2048; i += 512) ((float*)hd1p)[i] = 0.f;
    for (int i = t; i < 1152; i += 512) {
        int s = i >> 7, rest = i & 127;
        int co = rest >> 4, ci = rest & 15;
        w2sT[i] = wd2[(ci * 8 + co) * 9 + s];
    }
    if (t < 72) {
        int s = t >> 3, ci = t & 7;
        w3sT[t] = wd3[ci * 9 + s];
    }
    __syncthreads();

    // wd1 MFMA + SCATTER epilogue: each P[pos][col] -> exactly one hd1p slot
    {
        f32x4 acc[3][2];
#pragma unroll
        for (int i = 0; i < 3; i++)
#pragma unroll
            for (int mt = 0; mt < 2; mt++) acc[i][mt] = (f32x4){0.f, 0.f, 0.f, 0.f};
        const s8v* B = (const s8v*)wd1frag;
        for (int k0 = 0; k0 < 8; k0++) {
            s8v a0 = *(const s8v*)&zAb[g * 8448 + lr * 264 + k0 * 32 + lg * 8];
            s8v a1 = *(const s8v*)&zAb[g * 8448 + (16 + lr) * 264 + k0 * 32 + lg * 8];
#pragma unroll
            for (int i = 0; i < 3; i++) {
                int nt = wv + 4 * i;
                if (nt < 9) {
                    s8v bb = B[(nt * 8 + k0) * 64 + l];
                    acc[i][0] = __builtin_amdgcn_mfma_f32_16x16x32_bf16(a0, bb, acc[i][0], 0, 0, 0);
                    acc[i][1] = __builtin_amdgcn_mfma_f32_16x16x32_bf16(a1, bb, acc[i][1], 0, 0, 0);
                }
            }
        }
        float* hbase = &hd1p[g][0][0];
#pragma unroll
        for (int i = 0; i < 3; i++) {
            int nt = wv + 4 * i;
            if (nt < 9) {
                int col = nt * 16 + lr;
                int co = col / 9, s = col % 9;
                int sy = s / 3, sx = s % 3;
#pragma unroll
                for (int mt = 0; mt < 2; mt++)
#pragma unroll
                    for (int r = 0; r < 4; r++) {
                        int pos = mt * 16 + lg * 4 + r;
                        if (pos < 25) {
                            int iy = pos / 5, ix = pos % 5;
                            atomicAdd(&hbase[co * 64 + (iy + sy) * 8 + (ix + sx)],
                                      acc[i][mt][r]);
                        }
                    }
            }
        }
    }
    __syncthreads();

    // bias + bn + relu in-place over hd1p valid slots
    for (int o = tg; o < 784; o += 256) {
        int co = o / 49, rr = o % 49, y = rr / 7, xx = rr % 7;
        float* p = &hd1p[g][co][y * 8 + xx];
        float v = (*p + bd1[co]) * (gd1[co] * bnr) + btd1[co];
        *p = fmaxf(v, 0.f);
    }
    __syncthreads();   // zAb dead; hd2p overlays dbuf

    // wd2: load-balanced piece assignment
    {
        if (t < 464) {
            int im = t / 232, rest = t % 232;
            int co = rest / 29, s = rest % 29;
            int yy = (s < 15) ? 14 : (s - 15);
            int xx2 = (s < 15) ? s : 14;
            ((float*)dbuf)[im * 1808 + co * 225 + yy * 15 + xx2] = 0.f;
        }
        if (l < 56 && (l & 7) < 7) {
            int r = l >> 3, c = l & 7;
            const float* hb = &hd1p[g][0][0];
            float* hout = (float*)dbuf + g * 1808;
            if (wv == 0) {
                wd2_piece<3, 4>(hb, hout, w2sT, bd2, gd2, btd2, bnr, r, c, 0);
                wd2_piece<0, 2>(hb, hout, w2sT, bd2, gd2, btd2, bnr, r, c, 0);
            } else if (wv == 1) {
                wd2_piece<3, 4>(hb, hout, w2sT, bd2, gd2, btd2, bnr, r, c, 4);
                wd2_piece<0, 2>(hb, hout, w2sT, bd2, gd2, btd2, bnr, r, c, 2);
            } else if (wv == 2) {
                wd2_piece<1, 8>(hb, hout, w2sT, bd2, gd2, btd2, bnr, r, c, 0);
                wd2_piece<0, 2>(hb, hout, w2sT, bd2, gd2, btd2, bnr, r, c, 4);
            } else {
                wd2_piece<2, 8>(hb, hout, w2sT, bd2, gd2, btd2, bnr, r, c, 0);
                wd2_piece<0, 2>(hb, hout, w2sT, bd2, gd2, btd2, bnr, r, c, 6);
            }
        }
    }
    __syncthreads();

    // wd3: load-balanced piece assignment
    {
        const float* h2b = (const float*)dbuf + g * 1808;
        float* og = out0 + (size_t)(b0 + g) * 784;
        float bd30 = bd3[0];
        if (wv == 0) {
            wd3_piece<3, 7>(h2b, w3sT, bd30, og, l, 0);
            wd3_piece<0, 7>(h2b, w3sT, bd30, og, l, 0);
        } else if (wv == 1) {
            wd3_piece<3, 7>(h2b, w3sT, bd30, og, l, 7);
            wd3_piece<0, 7>(h2b, w3sT, bd30, og, l, 7);
        } else if (wv == 2) {
            wd3_piece<1, 14>(h2b, w3sT, bd30, og, l, 0);
        } else {
            wd3_piece<2, 14>(h2b, w3sT, bd30, og, l, 0);
        }
    }
}

extern "C" void kernel_launch(void* const* d_in, const int* in_sizes, int n_in,
                              void* d_out, int out_size, void* d_ws, size_t ws_size,
                              hipStream_t stream) {
    const float* x    = (const float*)d_in[0];
    const float* w1   = (const float*)d_in[1];
    const float* b1   = (const float*)d_in[2];
    const float* w2   = (const float*)d_in[3];
    const float* b2   = (const float*)d_in[4];
    const float* g2   = (const float*)d_in[5];
    const float* bt2  = (const float*)d_in[6];
    const float* w3   = (const float*)d_in[7];
    const float* b3   = (const float*)d_in[8];
    const float* proto= (const float*)d_in[9];
    const float* wup  = (const float*)d_in[10];
    const float* bup  = (const float*)d_in[11];
    const float* gup  = (const float*)d_in[12];
    const float* btup = (const float*)d_in[13];
    const float* wd1  = (const float*)d_in[14];
    const float* bd1  = (const float*)d_in[15];
    const float* gd1  = (const float*)d_in[16];
    const float* btd1 = (const float*)d_in[17];
    const float* wd2  = (const float*)d_in[18];
    const float* bd2  = (const float*)d_in[19];
    const float* gd2  = (const float*)d_in[20];
    const float* btd2 = (const float*)d_in[21];
    const float* wd3  = (const float*)d_in[22];
    const float* bd3  = (const float*)d_in[23];

    float* out0   = (float*)d_out;                 // [4096][784]
    float* out_md = out0 + (size_t)NB * 784;       // [4096][512]

    // ws layout
    float*    p2      = (float*)d_ws;                          // 512 f
    float*    pad0    = p2 + 512;                              // reserved
    ushort_t* pfragHi = (ushort_t*)(pad0 + 131072);            // 131072
    ushort_t* pfragLo = pfragHi + 131072;                      // 131072
    ushort_t* w3fH    = pfragLo + 131072;                      // 40960
    ushort_t* w3fL    = w3fH + 40960;                          // 40960
    ushort_t* w2fH    = w3fL + 40960;                          // 1536
    ushort_t* w2fL    = w2fH + 1536;                           // 1536
    ushort_t* wd1frag = w2fL + 1536;                           // 36864
    ushort_t* wupfH   = wd1frag + 36864;                       // 1638400
    ushort_t* wupfL   = wupfH + 1638400;                       // 1638400
    ushort_t* PWfrag  = wupfL + 1638400;                       // 3276800
    ushort_t* Wsm     = PWfrag + 3276800;                      // 2097152
    ushort_t* BIG     = Wsm + 2097152;                         // 52.4 MB region
    ushort_t* h3g     = BIG;                                   // [4096][25][256] bf16
    ushort_t* zupT    = BIG;                                   // aliases dead h3g

    hipLaunchKernelGGL(k_pre, dim3(7734), dim3(256), 0, stream,
                       proto, p2, pfragHi, pfragLo, w3, w3fH, w3fL,
                       w2, w2fH, w2fL, wd1, wd1frag, wup, wupfH, wupfL);
    hipLaunchKernelGGL(k_pw2, dim3(25, 32), dim3(256), 0, stream,
                       pfragHi, pfragLo, wupfH, wupfL, PWfrag);
    hipLaunchKernelGGL(k_enc1, dim3(NB / 2), dim3(1024), 0, stream,
                       x, w1, b1, w2fH, w2fL, b2, g2, bt2, w3fH, w3fL, b3, h3g);
    hipLaunchKernelGGL(k_enc2, dim3(NB / 2), dim3(1024), 0, stream,
                       h3g, pfragHi, p2, out_md, Wsm);
    hipLaunchKernelGGL(k_zup2, dim3(50, 32), dim3(512), 0, stream,
                       Wsm, PWfrag, bup, gup, btup, zupT);
    hipLaunchKernelGGL(k_dtail, dim3(NB / 2), dim3(512), 0, stream,
                       zupT, wd1frag, bd1, gd1, btd1, wd2, bd2, gd2, btd2, wd3, bd3, out0);
}

// Round 23
// 236.978 us; speedup vs baseline: 1.2341x; 1.2341x over previous
//
#include <hip/hip_runtime.h>
#include <hip/hip_bf16.h>
#include <math.h>

#define NB 4096
#define DC 256
#define PC 512

typedef unsigned short ushort_t;
typedef __attribute__((ext_vector_type(4))) unsigned short us4;
typedef __attribute__((ext_vector_type(8))) unsigned short us8;
typedef __attribute__((ext_vector_type(8))) short s8v;       // bf16x8 for MFMA
typedef __attribute__((ext_vector_type(4))) float f32x4;

__device__ __forceinline__ float bf16_to_f(ushort_t u) {
    union { unsigned int i; float f; } c;
    c.i = ((unsigned int)u) << 16;
    return c.f;
}
__device__ __forceinline__ ushort_t f2bf(float f) {          // RNE
    union { float f; unsigned int u; } c; c.f = f;
    unsigned int r = c.u + 0x7fffu + ((c.u >> 16) & 1u);
    return (ushort_t)(r >> 16);
}

// ---------------- K_pre: all small packing kernels merged (blockIdx-range dispatch) -------
__global__ __launch_bounds__(256) void k_pre(
    const float* __restrict__ proto, float* __restrict__ p2,
    ushort_t* __restrict__ pfragHi, ushort_t* __restrict__ pfragLo,
    const float* __restrict__ w3, ushort_t* __restrict__ w3fH, ushort_t* __restrict__ w3fL,
    const float* __restrict__ w2, ushort_t* __restrict__ w2fH, ushort_t* __restrict__ w2fL,
    const float* __restrict__ wd1, ushort_t* __restrict__ wd1frag,
    const float* __restrict__ wup, ushort_t* __restrict__ wupfH, ushort_t* __restrict__ wupfL)
{
    int b = blockIdx.x, tid = threadIdx.x;
    __shared__ float red[256];
    if (b < 512) {
        int p = b, d = tid;
        float v = proto[p * DC + d];
        red[d] = v * v;
        __syncthreads();
        for (int s = 128; s > 0; s >>= 1) {
            if (d < s) red[d] += red[d + s];
            __syncthreads();
        }
        if (d == 0) p2[p] = red[0];
    } else if (b < 1024) {
        int idx = (b - 512) * 256 + tid;
        int j = idx & 7, l = (idx >> 3) & 63;
        int k0 = (idx >> 9) & 7, nt = idx >> 12;
        int n = nt * 16 + (l & 15);
        int k = k0 * 32 + (l >> 4) * 8 + j;
        float v = proto[n * DC + k];
        ushort_t hi = f2bf(v);
        pfragHi[idx] = hi;
        pfragLo[idx] = f2bf(v - bf16_to_f(hi));
    } else if (b < 1184) {
        int idx = (b - 1024) * 256 + tid;
        int j = idx & 7, l = (idx >> 3) & 63;
        int q = idx >> 9;
        int k0 = q % 5, nt = q / 5;
        int d = nt * 16 + (l & 15);
        int k = k0 * 32 + (l >> 4) * 8 + j;
        float v = (k < 144) ? w3[d * 144 + k] : 0.f;
        ushort_t hi = f2bf(v);
        w3fH[idx] = hi;
        w3fL[idx] = f2bf(v - bf16_to_f(hi));
    } else if (b < 1190) {
        int idx = (b - 1184) * 256 + tid;
        int j = idx & 7, l = (idx >> 3) & 63;
        int k0 = idx >> 9;
        int ch = l & 15;
        int k = k0 * 32 + (l >> 4) * 8 + j;
        float v = (k < 72) ? w2[ch * 72 + k] : 0.f;
        ushort_t hi = f2bf(v);
        w2fH[idx] = hi;
        w2fL[idx] = f2bf(v - bf16_to_f(hi));
    } else if (b < 1334) {
        int idx = (b - 1190) * 256 + tid;
        int j = idx & 7, l = (idx >> 3) & 63;
        int k0 = (idx >> 9) & 7, nt = idx >> 12;
        int n = nt * 16 + (l & 15);
        int k = k0 * 32 + (l >> 4) * 8 + j;
        wd1frag[idx] = f2bf(wd1[k * 144 + n]);
    } else {
        int idx = (b - 1334) * 256 + tid;
        int j = idx & 7, l = (idx >> 3) & 63;
        int k0 = (idx >> 9) & 7, nt = idx >> 12;
        int np = nt * 16 + (l & 15);
        int d = k0 * 32 + (l >> 4) * 8 + j;
        int pos = np >> 8, ch = np & 255;
        float v = wup[d * 6400 + ch * 25 + pos];
        ushort_t hi = f2bf(v);
        wupfH[idx] = hi;
        wupfL[idx] = f2bf(v - bf16_to_f(hi));
    }
}

// ---------------- K0f: PW = proto x wupT via MFMA (hi/lo), -> PWfrag [400][16][64][8] -----
__global__ __launch_bounds__(256) void k_pw2(
    const ushort_t* __restrict__ pfragHi, const ushort_t* __restrict__ pfragLo,
    const ushort_t* __restrict__ wupfH, const ushort_t* __restrict__ wupfL,
    ushort_t* __restrict__ PWfrag)
{
    int t = threadIdx.x;
    int w = t >> 6, l = t & 63, lr = l & 15, lg = l >> 4;
    int my = blockIdx.y;
    int ntb = blockIdx.x * 16 + w * 4;
    const s8v* AH = (const s8v*)pfragHi;
    const s8v* AL = (const s8v*)pfragLo;
    const s8v* BH = (const s8v*)wupfH;
    const s8v* BL = (const s8v*)wupfL;
    f32x4 acc[4];
#pragma unroll
    for (int q = 0; q < 4; q++) acc[q] = (f32x4){0.f, 0.f, 0.f, 0.f};
#pragma unroll
    for (int k0 = 0; k0 < 8; k0++) {
        s8v ah = AH[(my * 8 + k0) * 64 + l];
        s8v al = AL[(my * 8 + k0) * 64 + l];
#pragma unroll
        for (int q = 0; q < 4; q++) {
            s8v bh = BH[(size_t)((ntb + q) * 8 + k0) * 64 + l];
            s8v bl = BL[(size_t)((ntb + q) * 8 + k0) * 64 + l];
            acc[q] = __builtin_amdgcn_mfma_f32_16x16x32_bf16(ah, bh, acc[q], 0, 0, 0);
            acc[q] = __builtin_amdgcn_mfma_f32_16x16x32_bf16(al, bh, acc[q], 0, 0, 0);
            acc[q] = __builtin_amdgcn_mfma_f32_16x16x32_bf16(ah, bl, acc[q], 0, 0, 0);
        }
    }
#pragma unroll
    for (int q = 0; q < 4; q++) {
        int nt = ntb + q;
#pragma unroll
        for (int r = 0; r < 4; r++) {
            int p = my * 16 + lg * 4 + r;
            int k0p = p >> 5;
            int ll = ((p >> 3) & 3) * 16 + lr;
            int jj = p & 7;
            PWfrag[(((size_t)(nt * 16 + k0p) * 64) + ll) * 8 + jj] = f2bf(acc[q][r]);
        }
    }
}

// ---------------- E1: 2 img/block, 1024 thr; conv phases at 512 thr/img; coalesced store --
__global__ __launch_bounds__(1024) void k_enc1(
    const float* __restrict__ x,
    const float* __restrict__ w1, const float* __restrict__ b1,
    const ushort_t* __restrict__ w2fH, const ushort_t* __restrict__ w2fL,
    const float* __restrict__ b2,
    const float* __restrict__ g2, const float* __restrict__ bt2,
    const ushort_t* __restrict__ w3fH, const ushort_t* __restrict__ w3fL,
    const float* __restrict__ b3,
    ushort_t* __restrict__ h3g)        // [4096][25][256] bf16
{
    int b0 = blockIdx.x * 2;
    int t = threadIdx.x;
    int w = t >> 6, l = t & 63, lr = l & 15, lg = l >> 4;
    int tim = t >> 9, tt = t & 511;       // thread-half image

    __shared__ __align__(16) unsigned char buf[51712];
    unsigned char* bufI = buf + tim * 25856;
    float* xb = (float*)bufI;
    float* h1 = (float*)(bufI + 3136);
    ushort_t* im2Hi = (ushort_t*)(bufI + 9408);
    float* h2 = (float*)(bufI + 22720);
    ushort_t* imHi = (ushort_t*)bufI;

    const float bnr = rsqrtf(1.0f + 1e-5f);

    // phase 0: load x, zero im2col2 region
    const float* xg = x + (size_t)(b0 + tim) * 784;
    for (int i = tt; i < 784; i += 512) xb[i] = xg[i];
    for (int i = tt; i < 832; i += 512)
        ((float4*)(bufI + 9408))[i] = (float4){0.f, 0.f, 0.f, 0.f};
    __syncthreads();

    // phase 1: conv1 + scatter into im2col2 (single bf16), 512 thr/img
    for (int o = tt; o < 1568; o += 512) {
        int c = o / 196, r = o % 196, y = r / 14, xc = r % 14;
        float acc = b1[c];
        for (int sy = 0; sy < 3; sy++) {
            int iy = 2 * y - 1 + sy;
            if ((unsigned)iy >= 28u) continue;
            for (int sx = 0; sx < 3; sx++) {
                int ix = 2 * xc - 1 + sx;
                if ((unsigned)ix >= 28u) continue;
                acc += w1[c * 9 + sy * 3 + sx] * xb[iy * 28 + ix];
            }
        }
        float v = fmaxf(acc, 0.f);
        ushort_t hi = f2bf(v);
        int kb = c * 9;
        int yA, syA, xA, sxA, yB = 0, xB = 0;
        bool hasYB, hasXB;
        if (y & 1) { yA = y >> 1; syA = 2; yB = yA + 1; hasYB = (yB < 7); }
        else       { yA = y >> 1; syA = 1; hasYB = false; }
        if (xc & 1) { xA = xc >> 1; sxA = 2; xB = xA + 1; hasXB = (xB < 7); }
        else        { xA = xc >> 1; sxA = 1; hasXB = false; }
        im2Hi[(yA * 7 + xA) * 104 + kb + syA * 3 + sxA] = hi;
        if (hasXB) im2Hi[(yA * 7 + xB) * 104 + kb + syA * 3] = hi;
        if (hasYB) {
            im2Hi[(yB * 7 + xA) * 104 + kb + sxA] = hi;
            if (hasXB) im2Hi[(yB * 7 + xB) * 104 + kb] = hi;
        }
    }
    __syncthreads();

    // phase 2: conv2 as MFMA — waves (w&7)<4 of each half (4 m-tiles per image)
    if ((w & 7) < 4) {
        int w4 = w & 3;
        f32x4 cc = {0, 0, 0, 0};
        const s8v* WH = (const s8v*)w2fH;
        const s8v* WL = (const s8v*)w2fL;
#pragma unroll
        for (int k0 = 0; k0 < 3; k0++) {
            s8v a0 = *(const s8v*)&im2Hi[(w4 * 16 + lr) * 104 + k0 * 32 + lg * 8];
            s8v bh = WH[k0 * 64 + l];
            s8v bl = WL[k0 * 64 + l];
            cc = __builtin_amdgcn_mfma_f32_16x16x32_bf16(a0, bh, cc, 0, 0, 0);
            cc = __builtin_amdgcn_mfma_f32_16x16x32_bf16(a0, bl, cc, 0, 0, 0);
        }
        int ch = lr;
        float s = g2[ch] * bnr, bb = b2[ch], bt = bt2[ch];
#pragma unroll
        for (int r = 0; r < 4; r++) {
            int pos = w4 * 16 + lg * 4 + r;
            if (pos < 49)
                h2[ch * 49 + pos] = fmaxf((cc[r] + bb) * s + bt, 0.f);
        }
    }
    __syncthreads();

    // phase 3: scatter h2 -> im2col3 (single bf16) + extended k-tail zero guard
    if (tt < 64) imHi[3600 + tt] = 0;
    for (int o = tt; o < 784; o += 512) {
        float v = h2[o];
        int ci = o / 49, rr = o % 49, iy = rr / 7, ixp = rr % 7;
        ushort_t hi = f2bf(v);
        int kb = ci * 9;
#pragma unroll
        for (int sy = 0; sy < 3; sy++) {
            int py = iy - sy;
            if ((unsigned)py < 5u) {
#pragma unroll
                for (int sx = 0; sx < 3; sx++) {
                    int px = ixp - sx;
                    if ((unsigned)px < 5u)
                        imHi[(py * 5 + px) * 144 + kb + sy * 3 + sx] = hi;
                }
            }
        }
    }
    __syncthreads();

    // phase 4: conv3 as MFMA — wave w owns nt=w for BOTH images (16 waves = 16 nt)
    {
        const ushort_t* imHi0 = (const ushort_t*)buf;
        const ushort_t* imHi1 = (const ushort_t*)(buf + 25856);
        int nt = w;
        f32x4 c[2][2];   // [im][mt]
#pragma unroll
        for (int im = 0; im < 2; im++)
#pragma unroll
            for (int mt = 0; mt < 2; mt++) c[im][mt] = (f32x4){0.f, 0.f, 0.f, 0.f};
        const s8v* WH = (const s8v*)w3fH;
        const s8v* WL = (const s8v*)w3fL;
#pragma unroll
        for (int k0 = 0; k0 < 5; k0++) {
            s8v a00 = *(const s8v*)&imHi0[lr * 144 + k0 * 32 + lg * 8];
            s8v a01 = *(const s8v*)&imHi0[(16 + lr) * 144 + k0 * 32 + lg * 8];
            s8v a10 = *(const s8v*)&imHi1[lr * 144 + k0 * 32 + lg * 8];
            s8v a11 = *(const s8v*)&imHi1[(16 + lr) * 144 + k0 * 32 + lg * 8];
            s8v bh = WH[(nt * 5 + k0) * 64 + l];
            s8v bl = WL[(nt * 5 + k0) * 64 + l];
            c[0][0] = __builtin_amdgcn_mfma_f32_16x16x32_bf16(a00, bh, c[0][0], 0, 0, 0);
            c[0][1] = __builtin_amdgcn_mfma_f32_16x16x32_bf16(a01, bh, c[0][1], 0, 0, 0);
            c[0][0] = __builtin_amdgcn_mfma_f32_16x16x32_bf16(a00, bl, c[0][0], 0, 0, 0);
            c[0][1] = __builtin_amdgcn_mfma_f32_16x16x32_bf16(a01, bl, c[0][1], 0, 0, 0);
            c[1][0] = __builtin_amdgcn_mfma_f32_16x16x32_bf16(a10, bh, c[1][0], 0, 0, 0);
            c[1][1] = __builtin_amdgcn_mfma_f32_16x16x32_bf16(a11, bh, c[1][1], 0, 0, 0);
            c[1][0] = __builtin_amdgcn_mfma_f32_16x16x32_bf16(a10, bl, c[1][0], 0, 0, 0);
            c[1][1] = __builtin_amdgcn_mfma_f32_16x16x32_bf16(a11, bl, c[1][1], 0, 0, 0);
        }
        __syncthreads();   // all A-reads done; h3s overlays imHi regions
        int d = nt * 16 + lr;
        float bb = b3[d];
#pragma unroll
        for (int im = 0; im < 2; im++) {
            ushort_t* hs = (ushort_t*)(buf + im * 25856);
#pragma unroll
            for (int mt = 0; mt < 2; mt++) {
                f32x4 cv = c[im][mt];
#pragma unroll
                for (int r = 0; r < 4; r++) {
                    int pos = mt * 16 + lg * 4 + r;
                    if (pos < 25) {
                        float h = fmaxf(cv[r] + bb, 0.f);
                        hs[pos * 256 + d] = f2bf(h);
                    }
                }
            }
        }
    }
    __syncthreads();

    // phase 5: coalesced us8 copy LDS h3s -> global h3g
    for (int i = t; i < 1600; i += 1024) {
        int im = i >= 800 ? 1 : 0;
        int idx = im ? i - 800 : i;
        *(us8*)&h3g[(size_t)(b0 + im) * 6400 + idx * 8] =
            *(const us8*)((const ushort_t*)(buf + im * 25856) + idx * 8);
    }
}

// ---------------- E2: MFMA distances + softmax (2 img/block; proto HI-ONLY) --------------
__global__ __launch_bounds__(1024) void k_enc2(
    const ushort_t* __restrict__ h3g,        // [4096][25][256] bf16
    const ushort_t* __restrict__ pfragHi,
    const float* __restrict__ p2,
    float* __restrict__ md_out,
    ushort_t* __restrict__ Wsm)
{
    int t = threadIdx.x;
    int b0 = blockIdx.x * 2;
    int w = t >> 6, l = t & 63, lr = l & 15, lg = l >> 4;

    __shared__ __align__(16) ushort_t h3s[2][32][264];   // 33792 B
    __shared__ float mds[2][512];
    __shared__ float x2sh[2][32];
    __shared__ float x2part[2][25][8];
    __shared__ float wred[2][16];

    for (int i = t; i < 2048; i += 1024) {
        int im = i >> 10, pos = (i >> 5) & 31, c8 = i & 31;
        us8 v = {0, 0, 0, 0, 0, 0, 0, 0};
        if (pos < 25)
            v = *(const us8*)&h3g[(size_t)(b0 + im) * 6400 + pos * 256 + c8 * 8];
        *(us8*)&h3s[im][pos][c8 * 8] = v;
    }
    __syncthreads();

    if (t < 400) {
        int im = t / 200, rest = t % 200;
        int pos = rest >> 3, ch = rest & 7;
        const ushort_t* hp = &h3s[im][pos][ch * 32];
        float s = 0.f;
#pragma unroll
        for (int i = 0; i < 32; i++) {
            float f = bf16_to_f(hp[i]);
            s = fmaf(f, f, s);
        }
        x2part[im][pos][ch] = s;
    }
    __syncthreads();
    if (t < 64) {
        int im = t >> 5, pos = t & 31;
        float s = 1e30f;
        if (pos < 25) {
            s = 0.f;
#pragma unroll
            for (int c = 0; c < 8; c++) s += x2part[im][pos][c];
        }
        x2sh[im][pos] = s;
    }
    __syncthreads();

    {
        f32x4 acc[2][2][2];
#pragma unroll
        for (int i = 0; i < 2; i++)
#pragma unroll
            for (int jm = 0; jm < 2; jm++)
#pragma unroll
                for (int mt = 0; mt < 2; mt++) acc[i][jm][mt] = (f32x4){0.f, 0.f, 0.f, 0.f};
        const s8v* BH = (const s8v*)pfragHi;
        s8v bhc[2], bhn[2];
#pragma unroll
        for (int ntq = 0; ntq < 2; ntq++) {
            int nt = w * 2 + ntq;
            bhc[ntq] = BH[(nt * 8 + 0) * 64 + l];
        }
        for (int k0 = 0; k0 < 8; k0++) {
            if (k0 < 7) {
#pragma unroll
                for (int ntq = 0; ntq < 2; ntq++) {
                    int nt = w * 2 + ntq;
                    bhn[ntq] = BH[(nt * 8 + k0 + 1) * 64 + l];
                }
            }
            s8v ah[2][2];
            ah[0][0] = *(const s8v*)&h3s[0][lr][k0 * 32 + lg * 8];
            ah[0][1] = *(const s8v*)&h3s[0][16 + lr][k0 * 32 + lg * 8];
            ah[1][0] = *(const s8v*)&h3s[1][lr][k0 * 32 + lg * 8];
            ah[1][1] = *(const s8v*)&h3s[1][16 + lr][k0 * 32 + lg * 8];
#pragma unroll
            for (int ntq = 0; ntq < 2; ntq++) {
                s8v bh = bhc[ntq];
#pragma unroll
                for (int im = 0; im < 2; im++) {
                    acc[ntq][im][0] = __builtin_amdgcn_mfma_f32_16x16x32_bf16(ah[im][0], bh, acc[ntq][im][0], 0, 0, 0);
                    acc[ntq][im][1] = __builtin_amdgcn_mfma_f32_16x16x32_bf16(ah[im][1], bh, acc[ntq][im][1], 0, 0, 0);
                }
            }
#pragma unroll
            for (int ntq = 0; ntq < 2; ntq++) bhc[ntq] = bhn[ntq];
        }
        float x2r[2][8];
#pragma unroll
        for (int im = 0; im < 2; im++)
#pragma unroll
            for (int r = 0; r < 4; r++) {
                x2r[im][r]     = x2sh[im][lg * 4 + r];
                x2r[im][4 + r] = x2sh[im][16 + lg * 4 + r];
            }
#pragma unroll
        for (int ntq = 0; ntq < 2; ntq++) {
            int pcol = (w * 2 + ntq) * 16 + lr;
            float p2v = p2[pcol];
#pragma unroll
            for (int im = 0; im < 2; im++) {
                float mm = 1e30f;
#pragma unroll
                for (int r = 0; r < 4; r++) {
                    float d0 = fmaxf(x2r[im][r]     - 2.f * acc[ntq][im][0][r] + p2v, 0.f);
                    float d1 = fmaxf(x2r[im][4 + r] - 2.f * acc[ntq][im][1][r] + p2v, 0.f);
                    mm = fminf(mm, fminf(d0, d1));
                }
                mm = fminf(mm, __shfl_xor(mm, 16));
                mm = fminf(mm, __shfl_xor(mm, 32));
                if (lg == 0) mds[im][pcol] = mm;
            }
        }
    }
    __syncthreads();

    int img = t >> 9, tt = t & 511;
    float mind = mds[img][tt];
    md_out[(size_t)(b0 + img) * PC + tt] = mind;
    float a = -mind;
    float mx = a;
#pragma unroll
    for (int off = 1; off < 64; off <<= 1) mx = fmaxf(mx, __shfl_xor(mx, off));
    int wv = w & 7;
    if (l == 0) wred[img][wv] = mx;
    __syncthreads();
    float m = wred[img][0];
#pragma unroll
    for (int i = 1; i < 8; i++) m = fmaxf(m, wred[img][i]);
    float e = expf(a - m);
    float sm = e;
#pragma unroll
    for (int off = 1; off < 64; off <<= 1) sm += __shfl_xor(sm, off);
    if (l == 0) wred[img][8 + wv] = sm;
    __syncthreads();
    float ssum = wred[img][8];
#pragma unroll
    for (int i = 9; i < 16; i++) ssum += wred[img][i];
    Wsm[(size_t)(b0 + img) * PC + tt] = f2bf(e / ssum);
}

// ---------------- K2: zupT = Wsm x PW (bf16 MFMA, 2-slab staging), bias+bn+relu ----------
__global__ __launch_bounds__(512) void k_zup2(
    const ushort_t* __restrict__ Wsm,      // [4096][512]
    const ushort_t* __restrict__ PWfrag,   // [400][16][64][8]
    const float* __restrict__ bup, const float* __restrict__ gup,
    const float* __restrict__ btup,
    ushort_t* __restrict__ zupT)           // [4096][6400]
{
    __shared__ __align__(16) ushort_t Bsh[2][8192];
    int t = threadIdx.x;
    int w = t >> 6, l = t & 63;
    int n0 = blockIdx.x * 128;             // 50
    int m0 = blockIdx.y * 128;             // 32
    int row = m0 + w * 16 + (l & 15);
    int krow = (l >> 4) * 8;
    f32x4 acc[8];
#pragma unroll
    for (int i = 0; i < 8; i++) acc[i] = (f32x4){0.f, 0.f, 0.f, 0.f};
    const s8v* B = (const s8v*)PWfrag;
    int base = blockIdx.x * 8 * 16;

    {
        s8v v0 = B[(size_t)(base + (t >> 6) * 16 + 0) * 64 + (t & 63)];
        s8v v1 = B[(size_t)(base + (t >> 6) * 16 + 1) * 64 + (t & 63)];
        *(s8v*)&Bsh[0][t * 8] = v0;
        *(s8v*)&Bsh[0][4096 + t * 8] = v1;
    }
    __syncthreads();
    for (int r = 0; r < 8; r++) {
        int cur = r & 1;
        if (r < 7) {
            s8v v0 = B[(size_t)(base + (t >> 6) * 16 + 2 * r + 2) * 64 + (t & 63)];
            s8v v1 = B[(size_t)(base + (t >> 6) * 16 + 2 * r + 3) * 64 + (t & 63)];
            *(s8v*)&Bsh[cur ^ 1][t * 8] = v0;
            *(s8v*)&Bsh[cur ^ 1][4096 + t * 8] = v1;
        }
#pragma unroll
        for (int kk = 0; kk < 2; kk++) {
            int k0 = 2 * r + kk;
            s8v a = *(const s8v*)&Wsm[(size_t)row * 512 + k0 * 32 + krow];
#pragma unroll
            for (int nt = 0; nt < 8; nt++) {
                s8v bb = *(const s8v*)&Bsh[cur][kk * 4096 + (nt * 64 + l) * 8];
                acc[nt] = __builtin_amdgcn_mfma_f32_16x16x32_bf16(a, bb, acc[nt], 0, 0, 0);
            }
        }
        __syncthreads();
    }

    const float bnr = rsqrtf(1.0f + 1e-5f);
    int rowbase = m0 + w * 16 + (l >> 4) * 4;
#pragma unroll
    for (int nt = 0; nt < 8; nt++) {
        int n = n0 + nt * 16 + (l & 15);
        int ch = n & 255;
        float sc = gup[ch] * bnr, bb = bup[ch], bt = btup[ch];
#pragma unroll
        for (int r = 0; r < 4; r++) {
            float v = (acc[nt][r] + bb) * sc + bt;
            zupT[(size_t)(rowbase + r) * 6400 + n] = f2bf(fmaxf(v, 0.f));
        }
    }
}

// ---------------- wd2/wd3 load-balanced class pieces ----------------
template<int CLS, int NCO>
__device__ __forceinline__ void wd2_piece(
    const float* hb, float* hout, const float* w2sT,
    const float* bd2, const float* gd2, const float* btd2,
    float bnr, int r, int c, int co0)
{
    const int cy = CLS >> 1, cx = CLS & 1;
    float acc[NCO];
#pragma unroll
    for (int q = 0; q < NCO; q++) acc[q] = 0.f;
#pragma unroll
    for (int ty = 0; ty < 1 + cy; ty++) {
        int iy = r + ty;
        int sy = cy ? (ty ? 0 : 2) : 1;
#pragma unroll
        for (int tx = 0; tx < 1 + cx; tx++) {
            int ix = c + tx;
            int sx = cx ? (tx ? 0 : 2) : 1;
            const float* wp = &w2sT[(sy * 3 + sx) * 128];
            int hoff = iy * 8 + ix;
            float h[16];
#pragma unroll
            for (int ci = 0; ci < 16; ci++) h[ci] = hb[ci * 64 + hoff];
#pragma unroll
            for (int q = 0; q < NCO; q++) {
                const float* wc = &wp[(co0 + q) * 16];
                float a = acc[q];
#pragma unroll
                for (int ci = 0; ci < 16; ci++) a = fmaf(h[ci], wc[ci], a);
                acc[q] = a;
            }
        }
    }
    int y = 2 * r + cy, x = 2 * c + cx;
#pragma unroll
    for (int q = 0; q < NCO; q++) {
        int co = co0 + q;
        float v = (acc[q] + bd2[co]) * (gd2[co] * bnr) + btd2[co];
        hout[co * 225 + y * 15 + x] = fmaxf(v, 0.f);
    }
}

template<int CLS, int NROW>
__device__ __forceinline__ void wd3_piece(
    const float* h2b, const float* w3sT, float bd30,
    float* og, int l, int row0)
{
    const int cy = CLS >> 1, cx = CLS & 1;
    const int NIT = (NROW * 16 + 63) / 64;
#pragma unroll
    for (int j = 0; j < NIT; j++) {
        int idx = l + 64 * j;
        int row = idx >> 4, col = idx & 15;
        if (row < NROW && col < 14) {
            int rr = row0 + row;
            float a = bd30;
#pragma unroll
            for (int ty = 0; ty < 1 + cy; ty++) {
                int iy = rr + ty;
                int sy = cy ? (ty ? 0 : 2) : 1;
#pragma unroll
                for (int tx = 0; tx < 1 + cx; tx++) {
                    int ix = col + tx;
                    int sx = cx ? (tx ? 0 : 2) : 1;
                    const float* wp = &w3sT[(sy * 3 + sx) * 8];
                    int hoff = iy * 15 + ix;
#pragma unroll
                    for (int ci = 0; ci < 8; ci++)
                        a = fmaf(h2b[ci * 225 + hoff], wp[ci], a);
                }
            }
            int y = 2 * rr + cy, x = 2 * col + cx;
            og[y * 28 + x] = 1.f / (1.f + expf(-a));
        }
    }
}

// ---------------- K3: fused decoder, 2 img/block, LOAD-BALANCED classes -------------------
__global__ __launch_bounds__(512) void k_dtail(
    const ushort_t* __restrict__ zupT,     // [4096][6400]
    const ushort_t* __restrict__ wd1frag,  // [9][8][64][8]
    const float* __restrict__ bd1, const float* __restrict__ gd1, const float* __restrict__ btd1,
    const float* __restrict__ wd2, const float* __restrict__ bd2,
    const float* __restrict__ gd2, const float* __restrict__ btd2,
    const float* __restrict__ wd3, const float* __restrict__ bd3,
    float* __restrict__ out0)
{
    int b0 = blockIdx.x * 2, t = threadIdx.x;
    int w = t >> 6, l = t & 63, lr = l & 15, lg = l >> 4;
    int g = w >> 2, wv = w & 3, tg = t & 255;
    __shared__ __align__(16) unsigned char dbuf[33792];
    __shared__ float hd1p[2][16][64];
    __shared__ float w2sT[9 * 8 * 16];
    __shared__ float w3sT[9 * 8];
    ushort_t* zAb = (ushort_t*)dbuf;
    float* Psb = (float*)dbuf;

    const float bnr = rsqrtf(1.0f + 1e-5f);

    for (int c = t; c < 1600; c += 512) {
        int im = c / 800, cc = c % 800;
        *(us8*)&zAb[im * 8448 + (cc >> 5) * 264 + (cc & 31) * 8] =
            *(const us8*)&zupT[(size_t)(b0 + im) * 6400 + cc * 8];
    }
    for (int i = t; i < 2048; i += 512) ((float*)hd1p)[i] = 0.f;
    for (int i = t; i < 1152; i += 512) {
        int s = i >> 7, rest = i & 127;
        int co = rest >> 4, ci = rest & 15;
        w2sT[i] = wd2[(ci * 8 + co) * 9 + s];
    }
    if (t < 72) {
        int s = t >> 3, ci = t & 7;
        w3sT[t] = wd3[ci * 9 + s];
    }
    __syncthreads();

    {
        f32x4 acc[3][2];
#pragma unroll
        for (int i = 0; i < 3; i++)
#pragma unroll
            for (int mt = 0; mt < 2; mt++) acc[i][mt] = (f32x4){0.f, 0.f, 0.f, 0.f};
        const s8v* B = (const s8v*)wd1frag;
        for (int k0 = 0; k0 < 8; k0++) {
            s8v a0 = *(const s8v*)&zAb[g * 8448 + lr * 264 + k0 * 32 + lg * 8];
            s8v a1 = *(const s8v*)&zAb[g * 8448 + (16 + lr) * 264 + k0 * 32 + lg * 8];
#pragma unroll
            for (int i = 0; i < 3; i++) {
                int nt = wv + 4 * i;
                if (nt < 9) {
                    s8v bb = B[(nt * 8 + k0) * 64 + l];
                    acc[i][0] = __builtin_amdgcn_mfma_f32_16x16x32_bf16(a0, bb, acc[i][0], 0, 0, 0);
                    acc[i][1] = __builtin_amdgcn_mfma_f32_16x16x32_bf16(a1, bb, acc[i][1], 0, 0, 0);
                }
            }
        }
        __syncthreads();
#pragma unroll
        for (int i = 0; i < 3; i++) {
            int nt = wv + 4 * i;
            if (nt < 9) {
                int col = nt * 16 + lr;
#pragma unroll
                for (int mt = 0; mt < 2; mt++)
#pragma unroll
                    for (int r = 0; r < 4; r++) {
                        int pos = mt * 16 + lg * 4 + r;
                        if (pos < 25) Psb[g * 3700 + pos * 148 + col] = acc[i][mt][r];
                    }
            }
        }
    }
    __syncthreads();

    for (int o = tg; o < 784; o += 256) {
        int co = o / 49, rr = o % 49, y = rr / 7, xx = rr % 7;
        float a = bd1[co];
        int sy0 = y - 4 > 0 ? y - 4 : 0, sy1 = y < 2 ? y : 2;
        for (int sy = sy0; sy <= sy1; sy++) {
            int iy = y - sy;
            int sx0 = xx - 4 > 0 ? xx - 4 : 0, sx1 = xx < 2 ? xx : 2;
            for (int sx = sx0; sx <= sx1; sx++) {
                int ix = xx - sx;
                a += Psb[g * 3700 + (iy * 5 + ix) * 148 + co * 9 + sy * 3 + sx];
            }
        }
        float v = a * (gd1[co] * bnr) + btd1[co];
        hd1p[g][co][y * 8 + xx] = fmaxf(v, 0.f);
    }
    __syncthreads();

    // wd2: load-balanced piece assignment
    {
        if (t < 464) {
            int im = t / 232, rest = t % 232;
            int co = rest / 29, s = rest % 29;
            int yy = (s < 15) ? 14 : (s - 15);
            int xx2 = (s < 15) ? s : 14;
            ((float*)dbuf)[im * 1808 + co * 225 + yy * 15 + xx2] = 0.f;
        }
        if (l < 56 && (l & 7) < 7) {
            int r = l >> 3, c = l & 7;
            const float* hb = &hd1p[g][0][0];
            float* hout = (float*)dbuf + g * 1808;
            if (wv == 0) {
                wd2_piece<3, 4>(hb, hout, w2sT, bd2, gd2, btd2, bnr, r, c, 0);
                wd2_piece<0, 2>(hb, hout, w2sT, bd2, gd2, btd2, bnr, r, c, 0);
            } else if (wv == 1) {
                wd2_piece<3, 4>(hb, hout, w2sT, bd2, gd2, btd2, bnr, r, c, 4);
                wd2_piece<0, 2>(hb, hout, w2sT, bd2, gd2, btd2, bnr, r, c, 2);
            } else if (wv == 2) {
                wd2_piece<1, 8>(hb, hout, w2sT, bd2, gd2, btd2, bnr, r, c, 0);
                wd2_piece<0, 2>(hb, hout, w2sT, bd2, gd2, btd2, bnr, r, c, 4);
            } else {
                wd2_piece<2, 8>(hb, hout, w2sT, bd2, gd2, btd2, bnr, r, c, 0);
                wd2_piece<0, 2>(hb, hout, w2sT, bd2, gd2, btd2, bnr, r, c, 6);
            }
        }
    }
    __syncthreads();

    // wd3: load-balanced piece assignment
    {
        const float* h2b = (const float*)dbuf + g * 1808;
        float* og = out0 + (size_t)(b0 + g) * 784;
        float bd30 = bd3[0];
        if (wv == 0) {
            wd3_piece<3, 7>(h2b, w3sT, bd30, og, l, 0);
            wd3_piece<0, 7>(h2b, w3sT, bd30, og, l, 0);
        } else if (wv == 1) {
            wd3_piece<3, 7>(h2b, w3sT, bd30, og, l, 7);
            wd3_piece<0, 7>(h2b, w3sT, bd30, og, l, 7);
        } else if (wv == 2) {
            wd3_piece<1, 14>(h2b, w3sT, bd30, og, l, 0);
        } else {
            wd3_piece<2, 14>(h2b, w3sT, bd30, og, l, 0);
        }
    }
}

extern "C" void kernel_launch(void* const* d_in, const int* in_sizes, int n_in,
                              void* d_out, int out_size, void* d_ws, size_t ws_size,
                              hipStream_t stream) {
    const float* x    = (const float*)d_in[0];
    const float* w1   = (const float*)d_in[1];
    const float* b1   = (const float*)d_in[2];
    const float* w2   = (const float*)d_in[3];
    const float* b2   = (const float*)d_in[4];
    const float* g2   = (const float*)d_in[5];
    const float* bt2  = (const float*)d_in[6];
    const float* w3   = (const float*)d_in[7];
    const float* b3   = (const float*)d_in[8];
    const float* proto= (const float*)d_in[9];
    const float* wup  = (const float*)d_in[10];
    const float* bup  = (const float*)d_in[11];
    const float* gup  = (const float*)d_in[12];
    const float* btup = (const float*)d_in[13];
    const float* wd1  = (const float*)d_in[14];
    const float* bd1  = (const float*)d_in[15];
    const float* gd1  = (const float*)d_in[16];
    const float* btd1 = (const float*)d_in[17];
    const float* wd2  = (const float*)d_in[18];
    const float* bd2  = (const float*)d_in[19];
    const float* gd2  = (const float*)d_in[20];
    const float* btd2 = (const float*)d_in[21];
    const float* wd3  = (const float*)d_in[22];
    const float* bd3  = (const float*)d_in[23];

    float* out0   = (float*)d_out;                 // [4096][784]
    float* out_md = out0 + (size_t)NB * 784;       // [4096][512]

    // ws layout
    float*    p2      = (float*)d_ws;                          // 512 f
    float*    pad0    = p2 + 512;                              // reserved
    ushort_t* pfragHi = (ushort_t*)(pad0 + 131072);            // 131072
    ushort_t* pfragLo = pfragHi + 131072;                      // 131072
    ushort_t* w3fH    = pfragLo + 131072;                      // 40960
    ushort_t* w3fL    = w3fH + 40960;                          // 40960
    ushort_t* w2fH    = w3fL + 40960;                          // 1536
    ushort_t* w2fL    = w2fH + 1536;                           // 1536
    ushort_t* wd1frag = w2fL + 1536;                           // 36864
    ushort_t* wupfH   = wd1frag + 36864;                       // 1638400
    ushort_t* wupfL   = wupfH + 1638400;                       // 1638400
    ushort_t* PWfrag  = wupfL + 1638400;                       // 3276800
    ushort_t* Wsm     = PWfrag + 3276800;                      // 2097152
    ushort_t* BIG     = Wsm + 2097152;                         // 52.4 MB region
    ushort_t* h3g     = BIG;                                   // [4096][25][256] bf16
    ushort_t* zupT    = BIG;                                   // aliases dead h3g

    hipLaunchKernelGGL(k_pre, dim3(7734), dim3(256), 0, stream,
                       proto, p2, pfragHi, pfragLo, w3, w3fH, w3fL,
                       w2, w2fH, w2fL, wd1, wd1frag, wup, wupfH, wupfL);
    hipLaunchKernelGGL(k_pw2, dim3(25, 32), dim3(256), 0, stream,
                       pfragHi, pfragLo, wupfH, wupfL, PWfrag);
    hipLaunchKernelGGL(k_enc1, dim3(NB / 2), dim3(1024), 0, stream,
                       x, w1, b1, w2fH, w2fL, b2, g2, bt2, w3fH, w3fL, b3, h3g);
    hipLaunchKernelGGL(k_enc2, dim3(NB / 2), dim3(1024), 0, stream,
                       h3g, pfragHi, p2, out_md, Wsm);
    hipLaunchKernelGGL(k_zup2, dim3(50, 32), dim3(512), 0, stream,
                       Wsm, PWfrag, bup, gup, btup, zupT);
    hipLaunchKernelGGL(k_dtail, dim3(NB / 2), dim3(512), 0, stream,
                       zupT, wd1frag, bd1, gd1, btd1, wd2, bd2, gd2, btd2, wd3, bd3, out0);
}